// Round 4
// baseline (112.996 us; speedup 1.0000x reference)
//
#include <hip/hip_runtime.h>

#define LQ 32
#define NH 8
#define HPD 16

__global__ __launch_bounds__(256) void rpe_kernel(
    const float* __restrict__ relpos,
    const float* __restrict__ qfeat,
    const float* __restrict__ scaling,
    const float* __restrict__ tx,
    const float* __restrict__ ty,
    const float* __restrict__ tz,
    float* __restrict__ out, int N)
{
    int n = blockIdx.x;
    if (n >= N) return;
    int t = threadIdx.x;      // 0..255
    int h = t & 7;            // head
    int l = t >> 3;           // position in L

    // per-(n,l) relative position -> quantized indices.
    // XLA semantics: x / 0.4f is canonicalized to x * RN(1/0.4f) == x * 2.5f.
    // f32 add with f32 constant, exact f32 multiply by 2.5, floor, clip.
    const float* rp = relpos + ((size_t)n * LQ + l) * 3;
    float rx = rp[0], ry = rp[1], rz = rp[2];

    float nx = (rx + 70.4f) * 2.5f;
    float ny = (ry + 80.0f) * 2.5f;
    float nz = (rz + 4.0f)  * 2.5f;
    int ix = (int)floorf(nx);
    int iy = (int)floorf(ny);
    int iz = (int)floorf(nz);
    ix = min(max(ix, 0), 352);
    iy = min(max(iy, 0), 400);
    iz = min(max(iz, 0), 20);

    // qf[n, h, 0..47]  (48 floats = 12 float4); reused by all 32 l's -> L1
    const float4* q  = (const float4*)(qfeat + ((size_t)n * NH + h) * 48);
    const float4* px = (const float4*)(tx + ((size_t)ix * NH + h) * HPD);
    const float4* py = (const float4*)(ty + ((size_t)iy * NH + h) * HPD);
    const float4* pz = (const float4*)(tz + ((size_t)iz * NH + h) * HPD);

    float acc = 0.f;
#pragma unroll
    for (int v = 0; v < 4; ++v) {
        float4 a = px[v]; float4 b = q[v];
        acc += a.x*b.x + a.y*b.y + a.z*b.z + a.w*b.w;
    }
#pragma unroll
    for (int v = 0; v < 4; ++v) {
        float4 a = py[v]; float4 b = q[4 + v];
        acc += a.x*b.x + a.y*b.y + a.z*b.z + a.w*b.w;
    }
#pragma unroll
    for (int v = 0; v < 4; ++v) {
        float4 a = pz[v]; float4 b = q[8 + v];
        acc += a.x*b.x + a.y*b.y + a.z*b.z + a.w*b.w;
    }

    out[(size_t)n * (LQ * NH) + t] = acc * scaling[0];
}

extern "C" void kernel_launch(void* const* d_in, const int* in_sizes, int n_in,
                              void* d_out, int out_size, void* d_ws, size_t ws_size,
                              hipStream_t stream) {
    const float* relpos  = (const float*)d_in[0];
    const float* qfeat   = (const float*)d_in[1];
    const float* scaling = (const float*)d_in[2];
    // d_in[3] = query_batch_cnt (unused by reference math)
    const float* tx      = (const float*)d_in[4];
    const float* ty      = (const float*)d_in[5];
    const float* tz      = (const float*)d_in[6];
    float* out           = (float*)d_out;

    int N = in_sizes[0] / (LQ * 3);   // 20000

    rpe_kernel<<<N, 256, 0, stream>>>(relpos, qfeat, scaling, tx, ty, tz, out, N);
}

// Round 5
// 68.161 us; speedup vs baseline: 1.6578x; 1.6578x over previous
//
#include <hip/hip_runtime.h>

#define NH   8
#define LQ   32
#define HPD  16
#define NB   8    // n per block
#define LPT  8    // l per thread
// block = 256 threads = lq(4) x n(8) x h(8); grid = N/NB blocks

__global__ __launch_bounds__(256) void rpe_kernel(
    const float* __restrict__ relpos,
    const float* __restrict__ qfeat,
    const float* __restrict__ scaling,
    const float* __restrict__ tx,
    const float* __restrict__ ty,
    const float* __restrict__ tz,
    float* __restrict__ out, int N)
{
    // packed byte-offset triples per (n_local, l); n-stride 132 words so
    // ds_read_b128 lanes (8 distinct n) land on distinct bank quads.
    __shared__ unsigned int idx_lds[NB * 132];

    const int n0 = blockIdx.x * NB;

    // ---- phase 1: one thread per (n_local, l) computes quantized indices ----
    {
        int p  = threadIdx.x;          // 0..255 = 8n x 32l
        int np = p >> 5;
        int lp = p & 31;
        int gn = n0 + np;
        if (gn < N) {
            const float* rp = relpos + ((size_t)gn * LQ + lp) * 3;
            float rx = rp[0], ry = rp[1], rz = rp[2];
            // XLA semantics: /0.4f canonicalized to *2.5f (exact), f32 add.
            int ix = (int)floorf((rx + 70.4f) * 2.5f);
            int iy = (int)floorf((ry + 80.0f) * 2.5f);
            int iz = (int)floorf((rz + 4.0f)  * 2.5f);
            ix = min(max(ix, 0), 352);
            iy = min(max(iy, 0), 400);
            iz = min(max(iz, 0), 20);
            uint4 o;                    // byte offsets of table rows (x512)
            o.x = (unsigned)ix << 9;
            o.y = (unsigned)iy << 9;
            o.z = (unsigned)iz << 9;
            o.w = 0u;
            *(uint4*)&idx_lds[np * 132 + lp * 4] = o;
        }
    }
    __syncthreads();

    // ---- phase 2: thread = (lq, n_local, h); qf row in registers ----
    int t  = threadIdx.x;
    int h  = t & 7;
    int nl = (t >> 3) & 7;
    int lq = t >> 6;                   // 0..3
    int gn = n0 + nl;
    if (gn >= N) return;

    const float4* q = (const float4*)(qfeat + ((size_t)gn * NH + h) * 48);
    float4 qv[12];
#pragma unroll
    for (int v = 0; v < 12; ++v) qv[v] = q[v];

    const float s = scaling[0];
    const char* txb = (const char*)tx + h * 64;   // h's 64B slice of each row
    const char* tyb = (const char*)ty + h * 64;
    const char* tzb = (const char*)tz + h * 64;
    float* outp = out + ((size_t)gn * LQ) * NH + h;

#pragma unroll 2
    for (int i = 0; i < LPT; ++i) {
        int l = lq * LPT + i;
        uint4 o = *(const uint4*)&idx_lds[nl * 132 + l * 4];
        const float4* px = (const float4*)(txb + o.x);
        const float4* py = (const float4*)(tyb + o.y);
        const float4* pz = (const float4*)(tzb + o.z);

        float acc = 0.f;
#pragma unroll
        for (int v = 0; v < 4; ++v) {
            float4 a = px[v]; float4 b = qv[v];
            acc += a.x*b.x + a.y*b.y + a.z*b.z + a.w*b.w;
        }
#pragma unroll
        for (int v = 0; v < 4; ++v) {
            float4 a = py[v]; float4 b = qv[4 + v];
            acc += a.x*b.x + a.y*b.y + a.z*b.z + a.w*b.w;
        }
#pragma unroll
        for (int v = 0; v < 4; ++v) {
            float4 a = pz[v]; float4 b = qv[8 + v];
            acc += a.x*b.x + a.y*b.y + a.z*b.z + a.w*b.w;
        }
        outp[(size_t)l * NH] = acc * s;
    }
}

extern "C" void kernel_launch(void* const* d_in, const int* in_sizes, int n_in,
                              void* d_out, int out_size, void* d_ws, size_t ws_size,
                              hipStream_t stream) {
    const float* relpos  = (const float*)d_in[0];
    const float* qfeat   = (const float*)d_in[1];
    const float* scaling = (const float*)d_in[2];
    // d_in[3] = query_batch_cnt (unused by reference math)
    const float* tx      = (const float*)d_in[4];
    const float* ty      = (const float*)d_in[5];
    const float* tz      = (const float*)d_in[6];
    float* out           = (float*)d_out;

    int N = in_sizes[0] / (LQ * 3);   // 20000
    int blocks = (N + NB - 1) / NB;   // 2500

    rpe_kernel<<<blocks, 256, 0, stream>>>(relpos, qfeat, scaling, tx, ty, tz, out, N);
}

// Round 6
// 43.969 us; speedup vs baseline: 2.5699x; 1.5502x over previous
//
#include <hip/hip_runtime.h>

#define NH 8
#define LQ 32
#define NB 8   // n per block: one n per half-wave (256 thr = 8 half-waves)

__global__ __launch_bounds__(256) void rpe_kernel(
    const float* __restrict__ relpos,
    const float* __restrict__ qfeat,
    const float* __restrict__ scaling,
    const float* __restrict__ tx,
    const float* __restrict__ ty,
    const float* __restrict__ tz,
    float* __restrict__ out, int N)
{
    int t  = threadIdx.x;
    int k  = t & 31;          // lane within half-wave: owns 16B piece k of a row
    int nl = t >> 5;          // 0..7
    int gn = blockIdx.x * NB + nl;
    if (gn >= N) return;

    int h  = k >> 2;          // head this lane's piece belongs to
    int d4 = k & 3;           // which float4 of the head's 16 dims

    // lane k computes the quantized indices for l = k (coalesced 12B/lane).
    // XLA semantics: /0.4f canonicalized to *2.5f (exact), f32 add.
    const float* rp = relpos + ((size_t)gn * LQ + k) * 3;
    float rx = rp[0], ry = rp[1], rz = rp[2];
    int ix = min(max((int)floorf((rx + 70.4f) * 2.5f), 0), 352);
    int iy = min(max((int)floorf((ry + 80.0f) * 2.5f), 0), 400);
    int iz = min(max((int)floorf((rz + 4.0f)  * 2.5f), 0), 20);
    unsigned packed = (unsigned)ix | ((unsigned)iy << 9) | ((unsigned)iz << 18);

    // qf pieces for this lane (one float4 per axis), hoisted for the whole n
    const float* qb = qfeat + (size_t)gn * (NH * 48) + h * 48 + d4 * 4;
    float4 qx = *(const float4*)(qb);
    float4 qy = *(const float4*)(qb + 16);
    float4 qz = *(const float4*)(qb + 32);

    const float s = scaling[0];
    const char* txb = (const char*)tx + k * 16;   // lane's 16B piece of any row
    const char* tyb = (const char*)ty + k * 16;
    const char* tzb = (const char*)tz + k * 16;
    float* outp = out + (size_t)gn * (LQ * NH);

#pragma unroll 4
    for (int l = 0; l < LQ; ++l) {
        unsigned p  = __shfl((int)packed, l, 32);
        unsigned jx = p & 511u;
        unsigned jy = (p >> 9) & 511u;
        unsigned jz = p >> 18;
        // contiguous 512B row reads across the half-wave (4 lines each)
        float4 ax = *(const float4*)(txb + ((size_t)jx << 9));
        float4 ay = *(const float4*)(tyb + ((size_t)jy << 9));
        float4 az = *(const float4*)(tzb + ((size_t)jz << 9));

        float acc = ax.x*qx.x + ax.y*qx.y + ax.z*qx.z + ax.w*qx.w
                  + ay.x*qy.x + ay.y*qy.y + ay.z*qy.z + ay.w*qy.w
                  + az.x*qz.x + az.y*qz.y + az.z*qz.z + az.w*qz.w;

        // reduce the 4-lane d-group -> full dot for head h
        acc += __shfl_xor(acc, 1, 32);
        acc += __shfl_xor(acc, 2, 32);

        if (d4 == 0) outp[l * NH + h] = acc * s;   // 8 consecutive floats
    }
}

extern "C" void kernel_launch(void* const* d_in, const int* in_sizes, int n_in,
                              void* d_out, int out_size, void* d_ws, size_t ws_size,
                              hipStream_t stream) {
    const float* relpos  = (const float*)d_in[0];
    const float* qfeat   = (const float*)d_in[1];
    const float* scaling = (const float*)d_in[2];
    // d_in[3] = query_batch_cnt (unused by reference math)
    const float* tx      = (const float*)d_in[4];
    const float* ty      = (const float*)d_in[5];
    const float* tz      = (const float*)d_in[6];
    float* out           = (float*)d_out;

    int N = in_sizes[0] / (LQ * 3);   // 20000
    int blocks = (N + NB - 1) / NB;   // 2500

    rpe_kernel<<<blocks, 256, 0, stream>>>(relpos, qfeat, scaling, tx, ty, tz, out, N);
}